// Round 22
// baseline (779.567 us; speedup 1.0000x reference)
//
#include <hip/hip_runtime.h>
#include <math.h>

#define DD 100

// DPP quad-perm add (ctrl literal)
#define DPP_ADD(v, ctrl) ((v) + __int_as_float(__builtin_amdgcn_update_dpp( \
    0, __float_as_int(v), (ctrl), 0xf, 0xf, true)))

__device__ __forceinline__ float blo(unsigned u){
  union { unsigned i; float f; } c; c.i = u << 16; return c.f;
}
__device__ __forceinline__ float bhi(unsigned u){
  union { unsigned i; float f; } c; c.i = u & 0xFFFF0000u; return c.f;
}
__device__ __forceinline__ unsigned short f2bf(float f){
  unsigned u = __float_as_uint(f);
  unsigned r = (u + 0x7FFFu + ((u >> 16) & 1u)) >> 16;
  return (unsigned short)r;
}
// Phi(z) = 0.5*(1+erf(z/sqrt2)), Abramowitz-Stegun 7.1.26 (|err| ~1e-6)
__device__ __forceinline__ float phi_fast(float z){
  float x  = z * 0.70710678118654752440f;
  float ax = fabsf(x);
  float t  = __builtin_amdgcn_rcpf(1.0f + 0.3275911f*ax);
  float p  = t*(0.254829592f + t*(-0.284496736f + t*(1.421413741f
           + t*(-1.453152027f + t*1.061405429f))));
  float e  = __expf(-ax*ax);
  float erfv = copysignf(1.0f - p*e, x);
  return 0.5f*(1.0f + erfv);
}
__device__ __forceinline__ float4 relu4(float4 v){
  return make_float4(fmaxf(v.x,0.f), fmaxf(v.y,0.f), fmaxf(v.z,0.f), fmaxf(v.w,0.f));
}

// ---------------- Kernel 0: fold gate weights (expert-half layout) -----------
// wfold2[(dim*2 + eh)*52 + (s*9 + e)]; eh=0 -> w_gate (cg), eh=1 -> w_noise
// (cn); s: 0=mem,1=rs,2=rr,3=x2,4=ns. 45 payload + 7 pad floats per slot.
// cat@W = mem@(W0+W3) + rs@(W1+W3) + rr@(W2+W3) + x2@W4 + ns@W5.
__global__ void k_fold(const float* __restrict__ wg, const float* __restrict__ wn,
                       float* __restrict__ wfold2)
{
  int idx = blockIdx.x*256 + threadIdx.x;
  if (idx >= 9000) return;
  int dim = idx/90, r = idx%90, eh = r/45, i = r%45, s = i/9, e = i%9;
  const float* W = eh ? wn : wg;
  int rowA = (s==0) ? dim : (s==1) ? 100+dim : (s==2) ? 200+dim
           : (s==3) ? 400+dim : 500+dim;
  float v = W[rowA*9 + e] + ((s < 3) ? W[(300+dim)*9 + e] : 0.f);
  wfold2[(dim*2 + eh)*52 + i] = v;
}

// ---------------- Kernel 1: gating -> gateinfo + loss partials ---------------
// Quad lanes = (dp, eh): dp = dim parity, eh = expert half. Each lane reads
// only its half's 45 weights per dim (12 b128) and feeds TWO rows per read
// -> 18.75 LDS instr/row (R15: 40). Accumulators 9x2=18/lane (expert split
// avoids R12/R21's 36 -> stays under the 128-VGPR cliff). Slot stride 52
// floats -> quad bank spans {0-3},{20-23},{8-11},{28-31}: conflict-free.
// 50 k-steps x 2 dims; aligned float2 feature loads (quad-broadcast).
__global__ __launch_bounds__(256) void k_gate(
    const float* __restrict__ memf, const float* __restrict__ recr,
    const float* __restrict__ spar, const float* __restrict__ nsrc,
    const float* __restrict__ noise, const float* __restrict__ degc,
    const float* __restrict__ wfold2, const int* __restrict__ degree,
    float4* __restrict__ gateinfo, float* __restrict__ partials, int B)
{
  __shared__ __align__(16) float sW2[200*52];   // 41.6 KB
  __shared__ __align__(8) float2 sCC[DD];
  __shared__ float sPart[4][18];

  for (int i = threadIdx.x; i < 10400; i += 256) sW2[i] = wfold2[i];
  for (int i = threadIdx.x; i < DD; i += 256)
    sCC[i] = make_float2(degc[2*i], degc[2*i+1]);
  __syncthreads();

  const int wave = threadIdx.x >> 6, lane = threadIdx.x & 63;
  const int fq = lane & 3, grp = lane >> 2;
  const int dp = fq & 1, eh = fq >> 1;

  const int rA = blockIdx.x*128 + wave*32 + grp*2;
  const int rB = rA + 1;
  const bool vA = rA < B, vB = rB < B;
  const int rcA = vA ? rA : B-1, rcB = vB ? rB : B-1;
  const float ldgA = __logf((float)degree[rcA] + 1.0f);
  const float ldgB = __logf((float)degree[rcB] + 1.0f);

  const float* pmA = memf + (size_t)rcA*DD;  const float* pmB = memf + (size_t)rcB*DD;
  const float* psA = spar + (size_t)rcA*4*DD;const float* psB = spar + (size_t)rcB*4*DD;
  const float* prA = recr + (size_t)rcA*4*DD;const float* prB = recr + (size_t)rcB*4*DD;
  const float* pnA = nsrc + (size_t)rcA*DD;  const float* pnB = nsrc + (size_t)rcB*DD;

  float accA[9], accB[9];
  #pragma unroll
  for (int e = 0; e < 9; e++){ accA[e]=0.f; accB[e]=0.f; }

  for (int k = 0; k < 50; k++){
    const int d2 = 2*k;            // even base dim; lane's dim = d2 + dp
    const int dim = d2 + dp;
    const float2 cc = sCC[dim];

    // ---- derive row A (one dim) ----
    float fA0, fA1, fA2, fA3, fA4;
    {
      float2 me = *(const float2*)(pmA + d2);
      float2 s0 = *(const float2*)(psA + 0*DD + d2);
      float2 s1 = *(const float2*)(psA + 1*DD + d2);
      float2 s2 = *(const float2*)(psA + 2*DD + d2);
      float2 s3 = *(const float2*)(psA + 3*DD + d2);
      float2 r0 = *(const float2*)(prA + 0*DD + d2);
      float2 r1 = *(const float2*)(prA + 1*DD + d2);
      float2 r2 = *(const float2*)(prA + 2*DD + d2);
      float2 r3 = *(const float2*)(prA + 3*DD + d2);
      float2 nv = *(const float2*)(pnA + d2);
      float mm = fmaxf(dp ? me.y : me.x, 0.f);
      float sa = (dp ? s0.y : s0.x) + (dp ? s1.y : s1.x)
               + (dp ? s2.y : s2.x) + (dp ? s3.y : s3.x);
      float rr = fmaxf(dp ? r0.y : r0.x, 0.f) + fmaxf(dp ? r1.y : r1.x, 0.f)
               + fmaxf(dp ? r2.y : r2.x, 0.f) + fmaxf(dp ? r3.y : r3.x, 0.f);
      fA0 = mm;
      fA1 = sa*0.25f*(cc.x + ldgA*cc.y);
      fA2 = rr*0.25f;
      fA3 = fA0*fA1*fA2;
      fA4 = dp ? nv.y : nv.x;
    }
    // ---- derive row B ----
    float fB0, fB1, fB2, fB3, fB4;
    {
      float2 me = *(const float2*)(pmB + d2);
      float2 s0 = *(const float2*)(psB + 0*DD + d2);
      float2 s1 = *(const float2*)(psB + 1*DD + d2);
      float2 s2 = *(const float2*)(psB + 2*DD + d2);
      float2 s3 = *(const float2*)(psB + 3*DD + d2);
      float2 r0 = *(const float2*)(prB + 0*DD + d2);
      float2 r1 = *(const float2*)(prB + 1*DD + d2);
      float2 r2 = *(const float2*)(prB + 2*DD + d2);
      float2 r3 = *(const float2*)(prB + 3*DD + d2);
      float2 nv = *(const float2*)(pnB + d2);
      float mm = fmaxf(dp ? me.y : me.x, 0.f);
      float sa = (dp ? s0.y : s0.x) + (dp ? s1.y : s1.x)
               + (dp ? s2.y : s2.x) + (dp ? s3.y : s3.x);
      float rr = fmaxf(dp ? r0.y : r0.x, 0.f) + fmaxf(dp ? r1.y : r1.x, 0.f)
               + fmaxf(dp ? r2.y : r2.x, 0.f) + fmaxf(dp ? r3.y : r3.x, 0.f);
      fB0 = mm;
      fB1 = sa*0.25f*(cc.x + ldgB*cc.y);
      fB2 = rr*0.25f;
      fB3 = fB0*fB1*fB2;
      fB4 = dp ? nv.y : nv.x;
    }

    // ---- weight walk: 12 b128 for this (dim, eh); each feeds both rows ----
    const float4* wp = (const float4*)(sW2 + (size_t)(dim*2 + eh)*52);
    #pragma unroll
    for (int tq = 0; tq < 12; tq++){
      float4 w = wp[tq];
      #pragma unroll
      for (int u = 0; u < 4; u++){
        const int i = 4*tq + u;
        if (i < 45){
          const int s = i/9, e = i%9;
          float wv = (u==0)?w.x:(u==1)?w.y:(u==2)?w.z:w.w;
          float dA = (s==0)?fA0:(s==1)?fA1:(s==2)?fA2:(s==3)?fA3:fA4;
          float dB = (s==0)?fB0:(s==1)?fB1:(s==2)?fB2:(s==3)?fB3:fB4;
          accA[e] += dA*wv;
          accB[e] += dB*wv;
        }
      }
    }
  }

  // reduce: xor1 sums dim-parities; xor2 exchanges expert halves.
  float cgA[9], cnA[9], cgB[9], cnB[9];
  #pragma unroll
  for (int e = 0; e < 9; e++){
    float sA = DPP_ADD(accA[e], 0xB1);        // sum over dp (quad_perm 1,0,3,2)
    float oA = __shfl_xor(sA, 2, 64);         // other expert-half's sum
    cgA[e] = eh ? oA : sA;
    cnA[e] = eh ? sA : oA;
    float sB = DPP_ADD(accB[e], 0xB1);
    float oB = __shfl_xor(sB, 2, 64);
    cgB[e] = eh ? oB : sB;
    cnB[e] = eh ? sB : oB;
  }

  // lanes fq<2 finalize row A, fq>=2 finalize row B (static selects)
  const bool selB = (fq >= 2);
  const int rowS = selB ? rB : rA;
  const bool vS = rowS < B;
  const int rcS = vS ? rowS : B-1;
  float fg[9], fn[9];
  #pragma unroll
  for (int e = 0; e < 9; e++){
    fg[e] = selB ? cgB[e] : cgA[e];
    fn[e] = selB ? cnB[e] : cnA[e];
  }

  float sdv[9], rsd[9], nz[9];
  #pragma unroll
  for (int e = 0; e < 9; e++){
    float x = fn[e];
    float spl = fmaxf(x, 0.f) + __logf(1.0f + __expf(-fabsf(x)));
    sdv[e] = spl + 0.01f;
    rsd[e] = __builtin_amdgcn_rcpf(sdv[e]);
    nz[e]  = fg[e] + noise[(size_t)rcS*9 + e] * sdv[e];
  }
  float v1 = -3.402823e38f, v2 = v1, v3 = v1; int i1 = -1, i2 = -1;
  #pragma unroll
  for (int e = 0; e < 9; e++){
    float v = nz[e];
    if (v > v1){ v3=v2; v2=v1; i2=i1; v1=v; i1=e; }
    else if (v > v2){ v3=v2; v2=v; i2=e; }
    else if (v > v3){ v3=v; }
  }
  float tt = __expf(v2 - v1);
  float g1 = __builtin_amdgcn_rcpf(1.0f + tt);
  float g2 = tt*g1;

  float ld[9], im[9];
  #pragma unroll
  for (int e = 0; e < 9; e++){
    float thr = (nz[e] > v3) ? v3 : v2;
    float z = (fg[e] - thr)*rsd[e] - 0.1f;               // GATE_MEAN = 0.1
    ld[e] = vS ? phi_fast(z) : 0.f;
    im[e] = vS ? ((e==i1) ? g1 : ((e==i2) ? g2 : 0.f)) : 0.f;
  }
  if ((fq & 1) == 0 && vS)   // fq==0 writes row A, fq==2 writes row B
    gateinfo[rowS] = make_float4(g1, g2, __int_as_float(i1), __int_as_float(i2));

  // butterfly: {4,8,16,32} sums the 16 groups; {2} merges row parities
  // (fq0/1 and fq2/3 are duplicates -> NO off=1).  [R21-verified pattern]
  #pragma unroll
  for (int e = 0; e < 9; e++){
    #pragma unroll
    for (int off = 4; off < 64; off <<= 1){
      ld[e] += __shfl_xor(ld[e], off, 64);
      im[e] += __shfl_xor(im[e], off, 64);
    }
    ld[e] += __shfl_xor(ld[e], 2, 64);
    im[e] += __shfl_xor(im[e], 2, 64);
  }
  if (lane == 0){
    #pragma unroll
    for (int e = 0; e < 9; e++){ sPart[wave][e] = im[e]; sPart[wave][9+e] = ld[e]; }
  }
  __syncthreads();
  if (threadIdx.x < 18){
    float s = sPart[0][threadIdx.x] + sPart[1][threadIdx.x]
            + sPart[2][threadIdx.x] + sPart[3][threadIdx.x];
    partials[blockIdx.x*18 + threadIdx.x] = s;
  }
}

// ---------------- Kernel 2: expert mix -> outm (reads only chosen experts) ---
__global__ __launch_bounds__(256) void k_mix(
    const float* __restrict__ memf, const float* __restrict__ recr,
    const float* __restrict__ spar, const float* __restrict__ degc,
    const int* __restrict__ degree, const float4* __restrict__ gateinfo,
    float* __restrict__ outm, int B)
{
  const int total = B*25;
  for (int idx = blockIdx.x*256 + threadIdx.x; idx < total; idx += gridDim.x*256){
    int row = idx / 25, q = idx - row*25;
    float4 gi = gateinfo[row];
    float gv[2] = {gi.x, gi.y};
    int   ei[2] = {__float_as_int(gi.z), __float_as_int(gi.w)};
    float4 acc = make_float4(0.f,0.f,0.f,0.f);
    #pragma unroll
    for (int s = 0; s < 2; s++){
      int e = ei[s]; float g = gv[s];
      float4 v;
      if (e == 0){
        v = relu4(*(const float4*)(memf + (size_t)row*DD + 4*q));
      } else if (e < 5){
        float ldg = __logf((float)degree[row] + 1.0f);
        float4 ca = *(const float4*)(degc + 8*q);       // c0,c1,c0,c1
        float4 cb = *(const float4*)(degc + 8*q + 4);
        float4 sv = *(const float4*)(spar + ((size_t)row*4 + (e-1))*DD + 4*q);
        v = make_float4(sv.x*(ca.x + ldg*ca.y), sv.y*(ca.z + ldg*ca.w),
                        sv.z*(cb.x + ldg*cb.y), sv.w*(cb.z + ldg*cb.w));
      } else {
        v = relu4(*(const float4*)(recr + ((size_t)row*4 + (e-5))*DD + 4*q));
      }
      acc.x += g*v.x; acc.y += g*v.y; acc.z += g*v.z; acc.w += g*v.w;
    }
    ((float4*)outm)[(size_t)row*25 + q] = acc;
  }
}

// ---------------- Kernel 3: deterministic loss reduction ---------------------
__global__ __launch_bounds__(1024) void k_loss(const float* __restrict__ partials,
                                               int nblk, float* __restrict__ dloss)
{
  __shared__ float sS[18][57];
  int t = threadIdx.x;
  if (t < 1008){
    int k = t % 18, c = t / 18;   // 56 chunks
    float s = 0.f;
    for (int b = c; b < nblk; b += 56) s += partials[b*18 + k];
    sS[k][c] = s;
  }
  __syncthreads();
  if (t < 18){
    float tot = 0.f;
    #pragma unroll
    for (int c = 0; c < 56; c++) tot += sS[t][c];
    sS[t][56] = tot;
  }
  __syncthreads();
  if (t == 0){
    float mi = 0.f, ml = 0.f;
    #pragma unroll
    for (int e = 0; e < 9; e++){ mi += sS[e][56]; ml += sS[9+e][56]; }
    mi *= (1.f/9.f); ml *= (1.f/9.f);
    float vi = 0.f, vl = 0.f;
    #pragma unroll
    for (int e = 0; e < 9; e++){
      float a = sS[e][56]   - mi; vi += a*a;
      float b = sS[9+e][56] - ml; vl += b*b;
    }
    vi *= (1.f/8.f); vl *= (1.f/8.f);   // ddof=1, n=9
    *dloss = 0.4f * (vi/(mi*mi + 1e-10f) + vl/(ml*ml + 1e-10f));
  }
}

// ---------------- Kernel 4: link-prediction head -----------------------------
__global__ __launch_bounds__(512) void k_edge(
    const float* __restrict__ om,
    const float* __restrict__ sw, const float* __restrict__ sb,
    const float* __restrict__ dw, const float* __restrict__ db,
    const float* __restrict__ ow, const float* __restrict__ ob,
    float* __restrict__ dout, int NE)
{
  __shared__ __align__(4) unsigned short sSW[DD*102];
  __shared__ __align__(4) unsigned short sDW[DD*102];
  __shared__ float sSB[DD], sDB[DD], sOW[DD];

  for (int i = threadIdx.x; i < DD*DD; i += 512){
    int k = i / DD, d = i % DD;
    sSW[d*102 + k] = f2bf(sw[i]);
    sDW[d*102 + k] = f2bf(dw[i]);
  }
  for (int i = threadIdx.x; i < DD; i += 512){ sSB[i]=sb[i]; sDB[i]=db[i]; sOW[i]=ow[i]; }
  __syncthreads();

  const int wave = threadIdx.x >> 6, lane = threadIdx.x & 63;
  const int grp = blockIdx.x*8 + wave;
  const int e0 = grp*4;
  if (e0 >= NE) return;
  const int e0u = __builtin_amdgcn_readfirstlane(e0);
  const float* oS = om + (size_t)e0u*DD;
  const float* oP = om + ((size_t)(NE  + e0u))*DD;
  const float* oN = om + ((size_t)(2*NE + e0u))*DD;
  const int d0 = lane, d1 = lane + 64;
  const bool h1 = (d1 < DD);
  const int dc1 = h1 ? d1 : 0;

  float aS[4][2], aP[4][2], aN[4][2];
  #pragma unroll
  for (int r = 0; r < 4; r++){
    aS[r][0]=0.f; aS[r][1]=0.f; aP[r][0]=0.f; aP[r][1]=0.f; aN[r][0]=0.f; aN[r][1]=0.f;
  }

  for (int k = 0; k < DD; k += 4){
    unsigned uA = *(const unsigned*)&sSW[d0 *102 + k];
    unsigned uB = *(const unsigned*)&sSW[d0 *102 + k + 2];
    unsigned uC = *(const unsigned*)&sSW[dc1*102 + k];
    unsigned uD = *(const unsigned*)&sSW[dc1*102 + k + 2];
    unsigned uE = *(const unsigned*)&sDW[d0 *102 + k];
    unsigned uF = *(const unsigned*)&sDW[d0 *102 + k + 2];
    unsigned uG = *(const unsigned*)&sDW[dc1*102 + k];
    unsigned uH = *(const unsigned*)&sDW[dc1*102 + k + 2];
    float wS00=blo(uA), wS01=bhi(uA), wS02=blo(uB), wS03=bhi(uB);
    float wS10=blo(uC), wS11=bhi(uC), wS12=blo(uD), wS13=bhi(uD);
    float wD00=blo(uE), wD01=bhi(uE), wD02=blo(uF), wD03=bhi(uF);
    float wD10=blo(uG), wD11=bhi(uG), wD12=blo(uH), wD13=bhi(uH);
    #pragma unroll
    for (int r = 0; r < 4; r++){
      float4 ov = *(const float4*)(oS + r*DD + k);
      float4 pv = *(const float4*)(oP + r*DD + k);
      float4 nv = *(const float4*)(oN + r*DD + k);
      aS[r][0] += ov.x*wS00 + ov.y*wS01 + ov.z*wS02 + ov.w*wS03;
      aS[r][1] += ov.x*wS10 + ov.y*wS11 + ov.z*wS12 + ov.w*wS13;
      aP[r][0] += pv.x*wD00 + pv.y*wD01 + pv.z*wD02 + pv.w*wD03;
      aP[r][1] += pv.x*wD10 + pv.y*wD11 + pv.z*wD12 + pv.w*wD13;
      aN[r][0] += nv.x*wD00 + nv.y*wD01 + nv.z*wD02 + nv.w*wD03;
      aN[r][1] += nv.x*wD10 + nv.y*wD11 + nv.z*wD12 + nv.w*wD13;
    }
  }

  float owa = sOW[d0], owb = sOW[dc1];
  float sba = sSB[d0], sbb = sSB[dc1];
  float dba = sDB[d0], dbb = sDB[dc1];
  float ob0 = ob[0];
  #pragma unroll
  for (int r = 0; r < 4; r++){
    float hs0 = aS[r][0] + sba, hp0 = aP[r][0] + dba, hn0 = aN[r][0] + dba;
    float tp = fmaxf(hs0 + hp0, 0.f)*owa;
    float tn = fmaxf(hs0 + hn0, 0.f)*owa;
    if (h1){
      float hs1 = aS[r][1] + sbb, hp1 = aP[r][1] + dbb, hn1 = aN[r][1] + dbb;
      tp += fmaxf(hs1 + hp1, 0.f)*owb;
      tn += fmaxf(hs1 + hn1, 0.f)*owb;
    }
    #pragma unroll
    for (int off = 32; off > 0; off >>= 1){
      tp += __shfl_xor(tp, off, 64);
      tn += __shfl_xor(tn, off, 64);
    }
    if (lane == 0){
      dout[e0 + r]      = tp + ob0;
      dout[NE + e0 + r] = tn + ob0;
    }
  }
}

extern "C" void kernel_launch(void* const* d_in, const int* in_sizes, int n_in,
                              void* d_out, int out_size, void* d_ws, size_t ws_size,
                              hipStream_t stream)
{
  (void)n_in; (void)out_size; (void)ws_size;
  const float* memf  = (const float*)d_in[0];
  const float* recr  = (const float*)d_in[1];
  const float* spar  = (const float*)d_in[2];
  const float* nsrc  = (const float*)d_in[3];
  const float* noise = (const float*)d_in[4];
  const float* degc  = (const float*)d_in[5];
  const float* wg    = (const float*)d_in[6];
  const float* wn    = (const float*)d_in[7];
  const float* sw    = (const float*)d_in[8];
  const float* sb    = (const float*)d_in[9];
  const float* dw    = (const float*)d_in[10];
  const float* db    = (const float*)d_in[11];
  const float* ow    = (const float*)d_in[12];
  const float* ob    = (const float*)d_in[13];
  const int*   deg   = (const int*)d_in[14];

  const int B  = in_sizes[0] / DD;     // 90000
  const int NE = B / 3;                // 30000
  const int blocksA = (B + 127) / 128; // 704 (128-row tiles, 32 rows/wave)

  float4* gateinfo = (float4*)d_ws;                      // B float4
  float*  outm     = (float*)(gateinfo + B);             // B*DD floats
  float*  partials = outm + (size_t)B*DD;                // blocksA*18
  float*  wfold2   = partials + (size_t)blocksA*18;      // 200*52 floats
  float*  dout     = (float*)d_out;

  k_fold<<<dim3(36), dim3(256), 0, stream>>>(wg, wn, wfold2);
  k_gate<<<dim3(blocksA), dim3(256), 0, stream>>>(memf, recr, spar, nsrc, noise,
                                                  degc, wfold2, deg, gateinfo,
                                                  partials, B);
  k_mix<<<dim3(2048), dim3(256), 0, stream>>>(memf, recr, spar, degc, deg,
                                              gateinfo, outm, B);
  k_loss<<<dim3(1), dim3(1024), 0, stream>>>(partials, blocksA, dout + 2*NE);
  const int blocks2 = (NE/4 + 7) / 8;  // 938
  k_edge<<<dim3(blocks2), dim3(512), 0, stream>>>(outm, sw, sb, dw, db, ow, ob, dout, NE);
}

// Round 23
// 256.800 us; speedup vs baseline: 3.0357x; 3.0357x over previous
//
#include <hip/hip_runtime.h>
#include <math.h>

#define DD 100
#define GGATE 1024

// DPP quad-perm add (ctrl literal)
#define DPP_ADD(v, ctrl) ((v) + __int_as_float(__builtin_amdgcn_update_dpp( \
    0, __float_as_int(v), (ctrl), 0xf, 0xf, true)))

__device__ __forceinline__ float blo(unsigned u){
  union { unsigned i; float f; } c; c.i = u << 16; return c.f;
}
__device__ __forceinline__ float bhi(unsigned u){
  union { unsigned i; float f; } c; c.i = u & 0xFFFF0000u; return c.f;
}
__device__ __forceinline__ unsigned short f2bf(float f){
  unsigned u = __float_as_uint(f);
  unsigned r = (u + 0x7FFFu + ((u >> 16) & 1u)) >> 16;
  return (unsigned short)r;
}
// Phi(z) = 0.5*(1+erf(z/sqrt2)), Abramowitz-Stegun 7.1.26 (|err| ~1e-6)
__device__ __forceinline__ float phi_fast(float z){
  float x  = z * 0.70710678118654752440f;
  float ax = fabsf(x);
  float t  = __builtin_amdgcn_rcpf(1.0f + 0.3275911f*ax);
  float p  = t*(0.254829592f + t*(-0.284496736f + t*(1.421413741f
           + t*(-1.453152027f + t*1.061405429f))));
  float e  = __expf(-ax*ax);
  float erfv = copysignf(1.0f - p*e, x);
  return 0.5f*(1.0f + erfv);
}
__device__ __forceinline__ float4 relu4(float4 v){
  return make_float4(fmaxf(v.x,0.f), fmaxf(v.y,0.f), fmaxf(v.z,0.f), fmaxf(v.w,0.f));
}

// ---------------- Kernel 0: fold gate weights ------------------------------
// wfold[dim*90 + s*18 + e], s: 0=mem,1=rs,2=rr,3=x2,4=ns; e<9 wg, e>=9 wn.
// cat@W = mem@(W0+W3) + rs@(W1+W3) + rr@(W2+W3) + x2@W4 + ns@W5.
__global__ void k_fold(const float* __restrict__ wg, const float* __restrict__ wn,
                       float* __restrict__ wfold)
{
  int idx = blockIdx.x*256 + threadIdx.x;
  if (idx >= 9000) return;
  int dim = idx/90, r = idx%90, s = r/18, e = r%18;
  const float* W = (e < 9) ? wg : wn;
  int ee = (e < 9) ? e : e-9;
  int rowA = (s==0) ? dim : (s==1) ? 100+dim : (s==2) ? 200+dim
           : (s==3) ? 400+dim : 500+dim;
  float v = W[rowA*9 + ee] + ((s < 3) ? W[(300+dim)*9 + ee] : 0.f);
  wfold[idx] = v;
}

// ---------------- Kernel 1: gating -> gateinfo + loss partials ---------------
// FINAL (R15 config, best of 22 rounds): 4 lanes/row, 16 rows/wave, persistent
// 1024 blocks, direct in-loop 64B-window loads (line-dense, 1.3x fetch),
// slot-remapped weight LDS: slot(d) = (d>>2)+25*(d&3) -> concurrent fq lanes
// on banks {+0,+28,+24,+20}. No launch-bounds min-waves hint (R2: spill),
// no prefetch (R13/R16: VGPR cliff), no fusion (R17: cache-cold re-gather).
__global__ __launch_bounds__(256) void k_gate(
    const float* __restrict__ memf, const float* __restrict__ recr,
    const float* __restrict__ spar, const float* __restrict__ nsrc,
    const float* __restrict__ noise, const float* __restrict__ degc,
    const float* __restrict__ wfold, const int* __restrict__ degree,
    float4* __restrict__ gateinfo, float* __restrict__ partials, int B)
{
  __shared__ __align__(16) float sWF[100*92];   // 36.8 KB, slot-mapped
  __shared__ __align__(16) float sC0[DD], sC1[DD];
  __shared__ float sPart[4][18];

  for (int i = threadIdx.x; i < 9000; i += 256){
    int d = i/90, r = i%90;
    int slot = (d>>2) + 25*(d&3);
    sWF[slot*92 + r] = wfold[i];
  }
  for (int i = threadIdx.x; i < DD; i += 256){ sC0[i]=degc[2*i]; sC1[i]=degc[2*i+1]; }
  __syncthreads();

  const int wave = threadIdx.x >> 6, lane = threadIdx.x & 63;
  const int fq = lane & 3, rl = lane >> 2;
  const float4* sC04 = (const float4*)sC0;
  const float4* sC14 = (const float4*)sC1;

  float ldA[9], imA[9];
  #pragma unroll
  for (int e = 0; e < 9; e++){ ldA[e]=0.f; imA[e]=0.f; }

  const int ntile = (B + 63) / 64;   // 1407
  for (int t = blockIdx.x; t < ntile; t += GGATE){
    const int row = t*64 + wave*16 + rl;
    const bool valid = row < B;
    const int rc = valid ? row : B-1;
    const float* pm = memf + (size_t)rc*DD;
    const float* ps = spar + (size_t)rc*4*DD;
    const float* pr = recr + (size_t)rc*4*DD;
    const float* pn = nsrc + (size_t)rc*DD;
    float ldg = __logf((float)degree[rc] + 1.0f);

    float cg[9], cn[9];
    #pragma unroll
    for (int e = 0; e < 9; e++){ cg[e]=0.f; cn[e]=0.f; }

    for (int k = 0; k < 7; k++){
      int c = fq + 4*k;
      float fz = (c < 25) ? 1.f : 0.f;
      int ce = (c < 25) ? c : 0;
      float4 me = *(const float4*)(pm + 4*ce);
      float4 s0 = *(const float4*)(ps + 0*DD + 4*ce);
      float4 s1 = *(const float4*)(ps + 1*DD + 4*ce);
      float4 s2 = *(const float4*)(ps + 2*DD + 4*ce);
      float4 s3 = *(const float4*)(ps + 3*DD + 4*ce);
      float4 r0 = *(const float4*)(pr + 0*DD + 4*ce);
      float4 r1 = *(const float4*)(pr + 1*DD + 4*ce);
      float4 r2 = *(const float4*)(pr + 2*DD + 4*ce);
      float4 r3 = *(const float4*)(pr + 3*DD + 4*ce);
      float4 nv = *(const float4*)(pn + 4*ce);
      float4 c04 = sC04[ce], c14 = sC14[ce];

      float4 m4 = relu4(me);
      float4 sc = make_float4(c04.x + ldg*c14.x, c04.y + ldg*c14.y,
                              c04.z + ldg*c14.z, c04.w + ldg*c14.w);
      float4 rs4 = make_float4((s0.x+s1.x+s2.x+s3.x)*0.25f*sc.x,
                               (s0.y+s1.y+s2.y+s3.y)*0.25f*sc.y,
                               (s0.z+s1.z+s2.z+s3.z)*0.25f*sc.z,
                               (s0.w+s1.w+s2.w+s3.w)*0.25f*sc.w);
      float4 a0 = relu4(r0), a1 = relu4(r1), a2 = relu4(r2), a3 = relu4(r3);
      float4 rr4 = make_float4((a0.x+a1.x+a2.x+a3.x)*0.25f,
                               (a0.y+a1.y+a2.y+a3.y)*0.25f,
                               (a0.z+a1.z+a2.z+a3.z)*0.25f,
                               (a0.w+a1.w+a2.w+a3.w)*0.25f);
      m4.x*=fz; m4.y*=fz; m4.z*=fz; m4.w*=fz;
      rs4.x*=fz; rs4.y*=fz; rs4.z*=fz; rs4.w*=fz;
      rr4.x*=fz; rr4.y*=fz; rr4.z*=fz; rr4.w*=fz;
      float4 ns4 = make_float4(nv.x*fz, nv.y*fz, nv.z*fz, nv.w*fz);
      float4 x24 = make_float4(m4.x*rs4.x*rr4.x, m4.y*rs4.y*rr4.y,
                               m4.z*rs4.z*rr4.z, m4.w*rs4.w*rr4.w);

      // weight walk: slot(4*ce+j) = ce + 25*j  (conflict-free banks)
      #pragma unroll
      for (int j = 0; j < 4; j++){
        const float der0 = (j==0)?m4.x :(j==1)?m4.y :(j==2)?m4.z :m4.w;
        const float der1 = (j==0)?rs4.x:(j==1)?rs4.y:(j==2)?rs4.z:rs4.w;
        const float der2 = (j==0)?rr4.x:(j==1)?rr4.y:(j==2)?rr4.z:rr4.w;
        const float der3 = (j==0)?x24.x:(j==1)?x24.y:(j==2)?x24.z:x24.w;
        const float der4 = (j==0)?ns4.x:(j==1)?ns4.y:(j==2)?ns4.z:ns4.w;
        const float4* wpj = (const float4*)(sWF + (ce + 25*j)*92);
        #pragma unroll
        for (int tq = 0; tq < 23; tq++){
          float4 w = wpj[tq];
          #pragma unroll
          for (int u = 0; u < 4; u++){
            const int ww = 4*tq + u;
            if (ww < 90){
              const int seg = ww/18, e = ww%18;
              float wv = (u==0)?w.x:(u==1)?w.y:(u==2)?w.z:w.w;
              float dv = (seg==0)?der0:(seg==1)?der1:(seg==2)?der2:(seg==3)?der3:der4;
              if (e < 9) cg[e] += dv*wv; else cn[e-9] += dv*wv;
            }
          }
        }
      }
    }

    // quad reduce: all 4 lanes of a group hold the row sums
    #pragma unroll
    for (int e = 0; e < 9; e++){
      cg[e] = DPP_ADD(cg[e], 0xB1); cg[e] = DPP_ADD(cg[e], 0x4E);
      cn[e] = DPP_ADD(cn[e], 0xB1); cn[e] = DPP_ADD(cn[e], 0x4E);
    }

    float sd[9], rsd[9], nz[9];
    #pragma unroll
    for (int e = 0; e < 9; e++){
      float x = cn[e];
      float spl = fmaxf(x, 0.f) + __logf(1.0f + __expf(-fabsf(x)));
      sd[e]  = spl + 0.01f;
      rsd[e] = __builtin_amdgcn_rcpf(sd[e]);
      nz[e]  = cg[e] + noise[(size_t)rc*9 + e] * sd[e];
    }
    float v1 = -3.402823e38f, v2 = v1, v3 = v1; int i1 = -1, i2 = -1;
    #pragma unroll
    for (int e = 0; e < 9; e++){
      float v = nz[e];
      if (v > v1){ v3=v2; v2=v1; i2=i1; v1=v; i1=e; }
      else if (v > v2){ v3=v2; v2=v; i2=e; }
      else if (v > v3){ v3=v; }
    }
    float tt = __expf(v2 - v1);
    float g1 = __builtin_amdgcn_rcpf(1.0f + tt);
    float g2 = tt*g1;
    if (valid){
      #pragma unroll
      for (int e = 0; e < 9; e++){
        float thr = (nz[e] > v3) ? v3 : v2;
        float z = (cg[e] - thr)*rsd[e] - 0.1f;           // GATE_MEAN = 0.1
        ldA[e] += phi_fast(z);
        imA[e] += (e==i1) ? g1 : ((e==i2) ? g2 : 0.f);
      }
      if (fq == 0)
        gateinfo[row] = make_float4(g1, g2, __int_as_float(i1), __int_as_float(i2));
    }
  }

  // reduce across the 16 groups (quad lanes hold identical values -> start at 4)
  #pragma unroll
  for (int e = 0; e < 9; e++){
    #pragma unroll
    for (int off = 4; off < 64; off <<= 1){
      ldA[e] += __shfl_xor(ldA[e], off, 64);
      imA[e] += __shfl_xor(imA[e], off, 64);
    }
  }
  if (lane == 0){
    #pragma unroll
    for (int e = 0; e < 9; e++){ sPart[wave][e] = imA[e]; sPart[wave][9+e] = ldA[e]; }
  }
  __syncthreads();
  if (threadIdx.x < 18){
    float s = sPart[0][threadIdx.x] + sPart[1][threadIdx.x]
            + sPart[2][threadIdx.x] + sPart[3][threadIdx.x];
    partials[blockIdx.x*18 + threadIdx.x] = s;
  }
}

// ---------------- Kernel 2: expert mix -> outm (reads only chosen experts) ---
__global__ __launch_bounds__(256) void k_mix(
    const float* __restrict__ memf, const float* __restrict__ recr,
    const float* __restrict__ spar, const float* __restrict__ degc,
    const int* __restrict__ degree, const float4* __restrict__ gateinfo,
    float* __restrict__ outm, int B)
{
  const int total = B*25;
  for (int idx = blockIdx.x*256 + threadIdx.x; idx < total; idx += gridDim.x*256){
    int row = idx / 25, q = idx - row*25;
    float4 gi = gateinfo[row];
    float gv[2] = {gi.x, gi.y};
    int   ei[2] = {__float_as_int(gi.z), __float_as_int(gi.w)};
    float4 acc = make_float4(0.f,0.f,0.f,0.f);
    #pragma unroll
    for (int s = 0; s < 2; s++){
      int e = ei[s]; float g = gv[s];
      float4 v;
      if (e == 0){
        v = relu4(*(const float4*)(memf + (size_t)row*DD + 4*q));
      } else if (e < 5){
        float ldg = __logf((float)degree[row] + 1.0f);
        float4 ca = *(const float4*)(degc + 8*q);       // c0,c1,c0,c1
        float4 cb = *(const float4*)(degc + 8*q + 4);
        float4 sv = *(const float4*)(spar + ((size_t)row*4 + (e-1))*DD + 4*q);
        v = make_float4(sv.x*(ca.x + ldg*ca.y), sv.y*(ca.z + ldg*ca.w),
                        sv.z*(cb.x + ldg*cb.y), sv.w*(cb.z + ldg*cb.w));
      } else {
        v = relu4(*(const float4*)(recr + ((size_t)row*4 + (e-5))*DD + 4*q));
      }
      acc.x += g*v.x; acc.y += g*v.y; acc.z += g*v.z; acc.w += g*v.w;
    }
    ((float4*)outm)[(size_t)row*25 + q] = acc;
  }
}

// ---------------- Kernel 3: deterministic loss reduction ---------------------
__global__ __launch_bounds__(1024) void k_loss(const float* __restrict__ partials,
                                               int nblk, float* __restrict__ dloss)
{
  __shared__ float sS[18][57];
  int t = threadIdx.x;
  if (t < 1008){
    int k = t % 18, c = t / 18;   // 56 chunks
    float s = 0.f;
    for (int b = c; b < nblk; b += 56) s += partials[b*18 + k];
    sS[k][c] = s;
  }
  __syncthreads();
  if (t < 18){
    float tot = 0.f;
    #pragma unroll
    for (int c = 0; c < 56; c++) tot += sS[t][c];
    sS[t][56] = tot;
  }
  __syncthreads();
  if (t == 0){
    float mi = 0.f, ml = 0.f;
    #pragma unroll
    for (int e = 0; e < 9; e++){ mi += sS[e][56]; ml += sS[9+e][56]; }
    mi *= (1.f/9.f); ml *= (1.f/9.f);
    float vi = 0.f, vl = 0.f;
    #pragma unroll
    for (int e = 0; e < 9; e++){
      float a = sS[e][56]   - mi; vi += a*a;
      float b = sS[9+e][56] - ml; vl += b*b;
    }
    vi *= (1.f/8.f); vl *= (1.f/8.f);   // ddof=1, n=9
    *dloss = 0.4f * (vi/(mi*mi + 1e-10f) + vl/(ml*ml + 1e-10f));
  }
}

// ---------------- Kernel 4: link-prediction head -----------------------------
__global__ __launch_bounds__(512) void k_edge(
    const float* __restrict__ om,
    const float* __restrict__ sw, const float* __restrict__ sb,
    const float* __restrict__ dw, const float* __restrict__ db,
    const float* __restrict__ ow, const float* __restrict__ ob,
    float* __restrict__ dout, int NE)
{
  __shared__ __align__(4) unsigned short sSW[DD*102];
  __shared__ __align__(4) unsigned short sDW[DD*102];
  __shared__ float sSB[DD], sDB[DD], sOW[DD];

  for (int i = threadIdx.x; i < DD*DD; i += 512){
    int k = i / DD, d = i % DD;
    sSW[d*102 + k] = f2bf(sw[i]);
    sDW[d*102 + k] = f2bf(dw[i]);
  }
  for (int i = threadIdx.x; i < DD; i += 512){ sSB[i]=sb[i]; sDB[i]=db[i]; sOW[i]=ow[i]; }
  __syncthreads();

  const int wave = threadIdx.x >> 6, lane = threadIdx.x & 63;
  const int grp = blockIdx.x*8 + wave;
  const int e0 = grp*4;
  if (e0 >= NE) return;
  const int e0u = __builtin_amdgcn_readfirstlane(e0);
  const float* oS = om + (size_t)e0u*DD;
  const float* oP = om + ((size_t)(NE  + e0u))*DD;
  const float* oN = om + ((size_t)(2*NE + e0u))*DD;
  const int d0 = lane, d1 = lane + 64;
  const bool h1 = (d1 < DD);
  const int dc1 = h1 ? d1 : 0;

  float aS[4][2], aP[4][2], aN[4][2];
  #pragma unroll
  for (int r = 0; r < 4; r++){
    aS[r][0]=0.f; aS[r][1]=0.f; aP[r][0]=0.f; aP[r][1]=0.f; aN[r][0]=0.f; aN[r][1]=0.f;
  }

  for (int k = 0; k < DD; k += 4){
    unsigned uA = *(const unsigned*)&sSW[d0 *102 + k];
    unsigned uB = *(const unsigned*)&sSW[d0 *102 + k + 2];
    unsigned uC = *(const unsigned*)&sSW[dc1*102 + k];
    unsigned uD = *(const unsigned*)&sSW[dc1*102 + k + 2];
    unsigned uE = *(const unsigned*)&sDW[d0 *102 + k];
    unsigned uF = *(const unsigned*)&sDW[d0 *102 + k + 2];
    unsigned uG = *(const unsigned*)&sDW[dc1*102 + k];
    unsigned uH = *(const unsigned*)&sDW[dc1*102 + k + 2];
    float wS00=blo(uA), wS01=bhi(uA), wS02=blo(uB), wS03=bhi(uB);
    float wS10=blo(uC), wS11=bhi(uC), wS12=blo(uD), wS13=bhi(uD);
    float wD00=blo(uE), wD01=bhi(uE), wD02=blo(uF), wD03=bhi(uF);
    float wD10=blo(uG), wD11=bhi(uG), wD12=blo(uH), wD13=bhi(uH);
    #pragma unroll
    for (int r = 0; r < 4; r++){
      float4 ov = *(const float4*)(oS + r*DD + k);
      float4 pv = *(const float4*)(oP + r*DD + k);
      float4 nv = *(const float4*)(oN + r*DD + k);
      aS[r][0] += ov.x*wS00 + ov.y*wS01 + ov.z*wS02 + ov.w*wS03;
      aS[r][1] += ov.x*wS10 + ov.y*wS11 + ov.z*wS12 + ov.w*wS13;
      aP[r][0] += pv.x*wD00 + pv.y*wD01 + pv.z*wD02 + pv.w*wD03;
      aP[r][1] += pv.x*wD10 + pv.y*wD11 + pv.z*wD12 + pv.w*wD13;
      aN[r][0] += nv.x*wD00 + nv.y*wD01 + nv.z*wD02 + nv.w*wD03;
      aN[r][1] += nv.x*wD10 + nv.y*wD11 + nv.z*wD12 + nv.w*wD13;
    }
  }

  float owa = sOW[d0], owb = sOW[dc1];
  float sba = sSB[d0], sbb = sSB[dc1];
  float dba = sDB[d0], dbb = sDB[dc1];
  float ob0 = ob[0];
  #pragma unroll
  for (int r = 0; r < 4; r++){
    float hs0 = aS[r][0] + sba, hp0 = aP[r][0] + dba, hn0 = aN[r][0] + dba;
    float tp = fmaxf(hs0 + hp0, 0.f)*owa;
    float tn = fmaxf(hs0 + hn0, 0.f)*owa;
    if (h1){
      float hs1 = aS[r][1] + sbb, hp1 = aP[r][1] + dbb, hn1 = aN[r][1] + dbb;
      tp += fmaxf(hs1 + hp1, 0.f)*owb;
      tn += fmaxf(hs1 + hn1, 0.f)*owb;
    }
    #pragma unroll
    for (int off = 32; off > 0; off >>= 1){
      tp += __shfl_xor(tp, off, 64);
      tn += __shfl_xor(tn, off, 64);
    }
    if (lane == 0){
      dout[e0 + r]      = tp + ob0;
      dout[NE + e0 + r] = tn + ob0;
    }
  }
}

extern "C" void kernel_launch(void* const* d_in, const int* in_sizes, int n_in,
                              void* d_out, int out_size, void* d_ws, size_t ws_size,
                              hipStream_t stream)
{
  (void)n_in; (void)out_size; (void)ws_size;
  const float* memf  = (const float*)d_in[0];
  const float* recr  = (const float*)d_in[1];
  const float* spar  = (const float*)d_in[2];
  const float* nsrc  = (const float*)d_in[3];
  const float* noise = (const float*)d_in[4];
  const float* degc  = (const float*)d_in[5];
  const float* wg    = (const float*)d_in[6];
  const float* wn    = (const float*)d_in[7];
  const float* sw    = (const float*)d_in[8];
  const float* sb    = (const float*)d_in[9];
  const float* dw    = (const float*)d_in[10];
  const float* db    = (const float*)d_in[11];
  const float* ow    = (const float*)d_in[12];
  const float* ob    = (const float*)d_in[13];
  const int*   deg   = (const int*)d_in[14];

  const int B  = in_sizes[0] / DD;     // 90000
  const int NE = B / 3;                // 30000

  float4* gateinfo = (float4*)d_ws;                      // B float4
  float*  outm     = (float*)(gateinfo + B);             // B*DD floats
  float*  partials = outm + (size_t)B*DD;                // GGATE*18
  float*  wfold    = partials + (size_t)GGATE*18;        // 9000 floats
  float*  dout     = (float*)d_out;

  k_fold<<<dim3(36), dim3(256), 0, stream>>>(wg, wn, wfold);
  k_gate<<<dim3(GGATE), dim3(256), 0, stream>>>(memf, recr, spar, nsrc, noise,
                                                degc, wfold, deg, gateinfo,
                                                partials, B);
  k_mix<<<dim3(2048), dim3(256), 0, stream>>>(memf, recr, spar, degc, deg,
                                              gateinfo, outm, B);
  k_loss<<<dim3(1), dim3(1024), 0, stream>>>(partials, GGATE, dout + 2*NE);
  const int blocks2 = (NE/4 + 7) / 8;  // 938
  k_edge<<<dim3(blocks2), dim3(512), 0, stream>>>(outm, sw, sb, dw, db, ow, ob, dout, NE);
}